// Round 1
// baseline (657.002 us; speedup 1.0000x reference)
//
#include <hip/hip_runtime.h>
#include <hip/hip_bf16.h>
#include <math.h>

#define NN   10000
#define HIDD 512
#define BP   4096
#define KPAD 10048      // 157 * 64
#define KITER1 157

typedef short bf16x8 __attribute__((ext_vector_type(8)));
typedef float f32x4  __attribute__((ext_vector_type(4)));
typedef unsigned short u16x4 __attribute__((ext_vector_type(4)));
typedef unsigned short u16x8 __attribute__((ext_vector_type(8)));

__device__ __forceinline__ unsigned short f2bf(float f) {
  union { float f; unsigned u; } v; v.f = f;
  unsigned r = v.u + 0x7FFFu + ((v.u >> 16) & 1u);   // RN-even
  return (unsigned short)(r >> 16);
}
__device__ __forceinline__ float bf2f(unsigned short u) {
  union { unsigned u; float f; } v; v.u = ((unsigned)u) << 16;
  return v.f;
}

// src f32 [K][512] -> dst bf16 [512][Kpadw], zero-padded for k in [K, Kpadw)
__global__ void transpose_cvt(const float* __restrict__ src, unsigned short* __restrict__ dst,
                              int K, int Kpadw) {
  __shared__ float tile[32][33];
  int k0 = blockIdx.x * 32, n0 = blockIdx.y * 32;
  int t = threadIdx.x, c = t & 31, r = t >> 5;
  #pragma unroll
  for (int i = 0; i < 4; ++i) {
    int k = k0 + r + i * 8;
    float v = (k < K) ? src[(size_t)k * 512 + (n0 + c)] : 0.f;
    tile[r + i * 8][c] = v;
  }
  __syncthreads();
  #pragma unroll
  for (int i = 0; i < 4; ++i) {
    int n = n0 + r + i * 8;
    dst[(size_t)n * Kpadw + (k0 + c)] = f2bf(tile[c][r + i * 8]);
  }
}

// C[M][ldc] (f32) = op( A[M][K] * BT[n][k]^T ).  Tile 128x64, BK=64, 4 waves (2x2) of 64x32.
// AKIND 0: A = f32, rows gathered via idxx/idxy (K = NN, zero-pad to KPAD)
// AKIND 1: A = bf16 dense [M][512]
template<int AKIND, int RELU>
__global__ __launch_bounds__(256)
void gemm_mfma(const void* __restrict__ Ap, const unsigned short* __restrict__ BT,
               float* __restrict__ C,
               const int* __restrict__ idxx, const int* __restrict__ idxy,
               int Kp, int ldc, int nK) {
  __shared__ char As[128 * 128];   // 128 rows x 64 bf16 (128 B), XOR-swizzled granules
  __shared__ char Bs[64 * 128];    // 64 rows (n) x 64 bf16
  const int tid  = threadIdx.x;
  const int lane = tid & 63;
  const int wave = tid >> 6;
  const int wm = wave >> 1, wn = wave & 1;
  const int m0 = blockIdx.y * 128;
  const int n0 = blockIdx.x * 64;

  const int sr = tid >> 1, sp = tid & 1;     // A staging: row, half
  const float* arow = nullptr;
  const unsigned short* arow16 = nullptr;
  if (AKIND == 0) {
    int m = m0 + sr;
    int g = (m < BP) ? idxx[m] : idxy[m - BP];
    arow = (const float*)Ap + (size_t)g * NN;
  } else {
    arow16 = (const unsigned short*)Ap + (size_t)(m0 + sr) * HIDD;
  }
  const int bn = tid >> 2;                   // B staging row (n), 4 threads/row
  const unsigned short* brow = BT + (size_t)(n0 + bn) * Kp;

  f32x4 acc[4][2];
  #pragma unroll
  for (int i = 0; i < 4; ++i)
    #pragma unroll
    for (int j = 0; j < 2; ++j) acc[i][j] = (f32x4){0.f, 0.f, 0.f, 0.f};

  float4 ar[8];
  u16x8  ar16[4];
  u16x8  br[2];

  auto LOADREGS = [&](int t) {
    int k0 = t * 64;
    if (AKIND == 0) {
      #pragma unroll
      for (int j = 0; j < 8; ++j) {
        int k = k0 + sp * 32 + j * 4;
        if (k < NN) ar[j] = *(const float4*)(arow + k);
        else        ar[j] = make_float4(0.f, 0.f, 0.f, 0.f);
      }
    } else {
      #pragma unroll
      for (int j = 0; j < 4; ++j) {
        int g = sp * 4 + j;
        ar16[j] = *(const u16x8*)(arow16 + k0 + g * 8);
      }
    }
    #pragma unroll
    for (int q = 0; q < 2; ++q) {
      int g = (tid & 3) * 2 + q;
      br[q] = *(const u16x8*)(brow + k0 + g * 8);
    }
  };

  auto WRITELDS = [&]() {
    if (AKIND == 0) {
      #pragma unroll
      for (int j = 0; j < 8; ++j) {
        int kl = sp * 32 + j * 4;
        int g  = kl >> 3;
        u16x4 o;
        o[0] = f2bf(ar[j].x); o[1] = f2bf(ar[j].y); o[2] = f2bf(ar[j].z); o[3] = f2bf(ar[j].w);
        *(u16x4*)(As + sr * 128 + ((g ^ (sr & 7)) << 4) + ((kl & 4) ? 8 : 0)) = o;
      }
    } else {
      #pragma unroll
      for (int j = 0; j < 4; ++j) {
        int g = sp * 4 + j;
        *(u16x8*)(As + sr * 128 + ((g ^ (sr & 7)) << 4)) = ar16[j];
      }
    }
    #pragma unroll
    for (int q = 0; q < 2; ++q) {
      int g = (tid & 3) * 2 + q;
      *(u16x8*)(Bs + bn * 128 + ((g ^ (bn & 7)) << 4)) = br[q];
    }
  };

  for (int t = 0; t < nK; ++t) {
    if (t == 0) LOADREGS(0);
    else __syncthreads();          // previous compute done reading LDS
    WRITELDS();
    if (t + 1 < nK) LOADREGS(t + 1);   // prefetch next tile during compute
    __syncthreads();
    #pragma unroll
    for (int ks = 0; ks < 2; ++ks) {
      bf16x8 af[4]; bf16x8 bfr[2];
      int kg = ks * 4 + (lane >> 4);
      #pragma unroll
      for (int i = 0; i < 4; ++i) {
        int r = wm * 64 + i * 16 + (lane & 15);
        af[i] = *(const bf16x8*)(As + r * 128 + ((kg ^ (r & 7)) << 4));
      }
      #pragma unroll
      for (int j = 0; j < 2; ++j) {
        int n = wn * 32 + j * 16 + (lane & 15);
        bfr[j] = *(const bf16x8*)(Bs + n * 128 + ((kg ^ (n & 7)) << 4));
      }
      #pragma unroll
      for (int i = 0; i < 4; ++i)
        #pragma unroll
        for (int j = 0; j < 2; ++j)
          acc[i][j] = __builtin_amdgcn_mfma_f32_16x16x32_bf16(af[i], bfr[j], acc[i][j], 0, 0, 0);
    }
  }

  #pragma unroll
  for (int i = 0; i < 4; ++i) {
    #pragma unroll
    for (int j = 0; j < 2; ++j) {
      int row = m0 + wm * 64 + i * 16 + ((lane >> 4) << 2);
      int col = n0 + wn * 32 + j * 16 + (lane & 15);
      #pragma unroll
      for (int rr = 0; rr < 4; ++rr) {
        float v = acc[i][j][rr];
        if (RELU) v = fmaxf(v, 0.f);
        C[(size_t)(row + rr) * ldc + col] = v;
      }
    }
  }
}

// x0 = bf16( (ex - ey)^2 / sqrt(512) ), P rows [0,4096)=ex, [4096,8192)=ey
__global__ void pair_combine(const float* __restrict__ P, unsigned short* __restrict__ xb) {
  int i = blockIdx.x * 256 + threadIdx.x;  // over 4096*512/4 float4 groups
  const float4 a = ((const float4*)P)[i];
  const float4 b = ((const float4*)(P + (size_t)BP * HIDD))[i];
  const float s = 0.04419417382415922f;    // 1/sqrt(512)
  u16x4 o; float d;
  d = a.x - b.x; o[0] = f2bf(d * d * s);
  d = a.y - b.y; o[1] = f2bf(d * d * s);
  d = a.z - b.z; o[2] = f2bf(d * d * s);
  d = a.w - b.w; o[3] = f2bf(d * d * s);
  ((u16x4*)xb)[i] = o;
}

// highway combine: xout = relu(hg[:, :512]+bh) * t + x * (1-t),  t = sigmoid(hg[:, 512:]+bg)
__global__ void hwy_elem(const float* __restrict__ hg, const unsigned short* __restrict__ xin,
                         const float* __restrict__ bh, const float* __restrict__ bg,
                         unsigned short* __restrict__ xout) {
  int i = blockIdx.x * 256 + threadIdx.x;  // 4096*512
  int m = i >> 9, h = i & 511;
  float hv = hg[(size_t)m * 1024 + h] + bh[h];
  hv = fmaxf(hv, 0.f);
  float gv = hg[(size_t)m * 1024 + 512 + h] + bg[h];
  float tv = 1.f / (1.f + expf(-gv));
  float xi = bf2f(xin[i]);
  xout[i] = f2bf(hv * tv + xi * (1.f - tv));
}

// logits + 2-class log_softmax, one wave per row
__global__ void logits_lsm(const unsigned short* __restrict__ x2, const float* __restrict__ Wl,
                           const float* __restrict__ bl, float* __restrict__ out) {
  int gw = (blockIdx.x * blockDim.x + threadIdx.x) >> 6;
  int lane = threadIdx.x & 63;
  const unsigned short* xr = x2 + (size_t)gw * HIDD;
  u16x8 xv = *(const u16x8*)(xr + lane * 8);
  float4 w0 = ((const float4*)Wl)[lane * 4 + 0];
  float4 w1 = ((const float4*)Wl)[lane * 4 + 1];
  float4 w2 = ((const float4*)Wl)[lane * 4 + 2];
  float4 w3 = ((const float4*)Wl)[lane * 4 + 3];
  float xs[8];
  #pragma unroll
  for (int j = 0; j < 8; ++j) xs[j] = bf2f(xv[j]);
  float s0 = xs[0]*w0.x + xs[1]*w0.z + xs[2]*w1.x + xs[3]*w1.z
           + xs[4]*w2.x + xs[5]*w2.z + xs[6]*w3.x + xs[7]*w3.z;
  float s1 = xs[0]*w0.y + xs[1]*w0.w + xs[2]*w1.y + xs[3]*w1.w
           + xs[4]*w2.y + xs[5]*w2.w + xs[6]*w3.y + xs[7]*w3.w;
  #pragma unroll
  for (int off = 32; off; off >>= 1) { s0 += __shfl_down(s0, off); s1 += __shfl_down(s1, off); }
  if (lane == 0) {
    float l0 = s0 + bl[0], l1 = s1 + bl[1];
    float mx = fmaxf(l0, l1);
    float lse = mx + logf(expf(l0 - mx) + expf(l1 - mx));
    out[(size_t)gw * 2 + 0] = l0 - lse;
    out[(size_t)gw * 2 + 1] = l1 - lse;
  }
}

extern "C" void kernel_launch(void* const* d_in, const int* in_sizes, int n_in,
                              void* d_out, int out_size, void* d_ws, size_t ws_size,
                              hipStream_t stream) {
  const float* A   = (const float*)d_in[0];
  const float* W1  = (const float*)d_in[1];
  const float* Wh0 = (const float*)d_in[2];
  const float* bh0 = (const float*)d_in[3];
  const float* Wg0 = (const float*)d_in[4];
  const float* bg0 = (const float*)d_in[5];
  const float* Wh1 = (const float*)d_in[6];
  const float* bh1 = (const float*)d_in[7];
  const float* Wg1 = (const float*)d_in[8];
  const float* bg1 = (const float*)d_in[9];
  const float* Wl  = (const float*)d_in[10];
  const float* bl  = (const float*)d_in[11];
  const int* idxx  = (const int*)d_in[12];
  const int* idxy  = (const int*)d_in[13];
  float* out = (float*)d_out;

  char* w = (char*)d_ws;
  auto carve = [&](size_t bytes) { char* p = w; w += (bytes + 255) & ~(size_t)255; return p; };
  unsigned short* W1T  = (unsigned short*)carve((size_t)512 * KPAD * 2);
  unsigned short* WcT0 = (unsigned short*)carve((size_t)1024 * 512 * 2);
  unsigned short* WcT1 = (unsigned short*)carve((size_t)1024 * 512 * 2);
  float* P             = (float*)carve((size_t)8192 * 512 * 4);
  unsigned short* xb0  = (unsigned short*)carve((size_t)4096 * 512 * 2);
  unsigned short* xb1  = (unsigned short*)carve((size_t)4096 * 512 * 2);
  unsigned short* xb2  = (unsigned short*)carve((size_t)4096 * 512 * 2);
  float* hg            = (float*)carve((size_t)4096 * 1024 * 4);

  // weight prep (runs every call; ~31 MB traffic total)
  transpose_cvt<<<dim3(KPAD / 32, 16), 256, 0, stream>>>(W1, W1T, NN, KPAD);
  transpose_cvt<<<dim3(16, 16), 256, 0, stream>>>(Wh0, WcT0, 512, 512);
  transpose_cvt<<<dim3(16, 16), 256, 0, stream>>>(Wg0, WcT0 + (size_t)512 * 512, 512, 512);
  transpose_cvt<<<dim3(16, 16), 256, 0, stream>>>(Wh1, WcT1, 512, 512);
  transpose_cvt<<<dim3(16, 16), 256, 0, stream>>>(Wg1, WcT1 + (size_t)512 * 512, 512, 512);

  // P = relu(A[gathered rows] @ W1)  [8192 x 512]
  gemm_mfma<0, 1><<<dim3(8, 64), 256, 0, stream>>>((const void*)A, W1T, P, idxx, idxy,
                                                   KPAD, 512, KITER1);
  pair_combine<<<dim3(2048), 256, 0, stream>>>(P, xb0);

  // highway layer 0
  gemm_mfma<1, 0><<<dim3(16, 32), 256, 0, stream>>>((const void*)xb0, WcT0, hg, nullptr, nullptr,
                                                    512, 1024, 8);
  hwy_elem<<<dim3(8192), 256, 0, stream>>>(hg, xb0, bh0, bg0, xb1);

  // highway layer 1
  gemm_mfma<1, 0><<<dim3(16, 32), 256, 0, stream>>>((const void*)xb1, WcT1, hg, nullptr, nullptr,
                                                    512, 1024, 8);
  hwy_elem<<<dim3(8192), 256, 0, stream>>>(hg, xb1, bh1, bg1, xb2);

  logits_lsm<<<dim3(1024), 256, 0, stream>>>(xb2, Wl, bl, out);
}

// Round 2
// 281.016 us; speedup vs baseline: 2.3379x; 2.3379x over previous
//
#include <hip/hip_runtime.h>
#include <hip/hip_bf16.h>
#include <math.h>

#define NN   10000
#define HIDD 512
#define BP   4096
#define KPAD 10048      // 157 * 64
#define KITER1 157
#define KSPLIT_MID 79   // iters [0,79) and [79,157)

typedef short bf16x8 __attribute__((ext_vector_type(8)));
typedef float f32x4  __attribute__((ext_vector_type(4)));
typedef unsigned short u16x4 __attribute__((ext_vector_type(4)));
typedef unsigned short u16x8 __attribute__((ext_vector_type(8)));

__device__ __forceinline__ unsigned short f2bf(float f) {
  union { float f; unsigned u; } v; v.f = f;
  unsigned r = v.u + 0x7FFFu + ((v.u >> 16) & 1u);   // RN-even
  return (unsigned short)(r >> 16);
}
__device__ __forceinline__ float bf2f(unsigned short u) {
  union { unsigned u; float f; } v; v.u = ((unsigned)u) << 16;
  return v.f;
}

// src f32 [K][512] -> dst bf16 [512][Kpadw], zero-padded for k in [K, Kpadw)
__global__ void transpose_cvt(const float* __restrict__ src, unsigned short* __restrict__ dst,
                              int K, int Kpadw) {
  __shared__ float tile[32][33];
  int k0 = blockIdx.x * 32, n0 = blockIdx.y * 32;
  int t = threadIdx.x, c = t & 31, r = t >> 5;
  #pragma unroll
  for (int i = 0; i < 4; ++i) {
    int k = k0 + r + i * 8;
    float v = (k < K) ? src[(size_t)k * 512 + (n0 + c)] : 0.f;
    tile[r + i * 8][c] = v;
  }
  __syncthreads();
  #pragma unroll
  for (int i = 0; i < 4; ++i) {
    int n = n0 + r + i * 8;
    dst[(size_t)n * Kpadw + (k0 + c)] = f2bf(tile[c][r + i * 8]);
  }
}

// Gather-GEMM: Ppart[ks][8192][512] += A[gather rows] @ W1T^T over K-chunk ks.
// Tile 64(m) x 512(n) x BK=64, 512 threads = 8 waves, wave-tile 64x64.
// A-rows read EXACTLY ONCE from HBM (BN = full 512).
__global__ __launch_bounds__(512, 2)
void gather_gemm(const float* __restrict__ A, const unsigned short* __restrict__ BT,
                 float* __restrict__ Ppart,
                 const int* __restrict__ idxx, const int* __restrict__ idxy) {
  __shared__ char As[64 * 128];    // 64 rows x 64 bf16 (128 B), XOR-swizzled 16B granules
  __shared__ char Bs[512 * 128];   // 512 n-rows x 64 bf16
  const int tid  = threadIdx.x;
  const int lane = tid & 63;
  const int wave = tid >> 6;                  // 0..7, owns n-range [wave*64, wave*64+64)
  const int m0   = blockIdx.y * 64;
  const int ksp  = blockIdx.x;                // 0 or 1
  const int t0   = ksp ? KSPLIT_MID : 0;
  const int t1   = ksp ? KITER1 : KSPLIT_MID;

  // A staging: 8 threads per row, each 8 consecutive floats
  const int sr = tid >> 3, sp = tid & 7;
  int m = m0 + sr;
  int g = (m < BP) ? idxx[m] : idxy[m - BP];
  const float* arow = A + (size_t)g * NN;
  // B staging: 1 thread per n-row, 128 B (8 granules)
  const unsigned short* brow = BT + (size_t)tid * KPAD;

  f32x4 acc[4][4];
  #pragma unroll
  for (int i = 0; i < 4; ++i)
    #pragma unroll
    for (int j = 0; j < 4; ++j) acc[i][j] = (f32x4){0.f, 0.f, 0.f, 0.f};

  float4 ar[2];
  u16x8  br[8];

  auto LOADREGS = [&](int t) {
    int k0 = t * 64;
    int ka = k0 + sp * 8;
    if (ka < NN) {
      ar[0] = *(const float4*)(arow + ka);
      ar[1] = *(const float4*)(arow + ka + 4);
    } else {
      ar[0] = make_float4(0.f, 0.f, 0.f, 0.f);
      ar[1] = make_float4(0.f, 0.f, 0.f, 0.f);
    }
    #pragma unroll
    for (int q = 0; q < 8; ++q) br[q] = *(const u16x8*)(brow + k0 + q * 8);
  };

  auto WRITELDS = [&]() {
    u16x8 o;
    o[0] = f2bf(ar[0].x); o[1] = f2bf(ar[0].y); o[2] = f2bf(ar[0].z); o[3] = f2bf(ar[0].w);
    o[4] = f2bf(ar[1].x); o[5] = f2bf(ar[1].y); o[6] = f2bf(ar[1].z); o[7] = f2bf(ar[1].w);
    *(u16x8*)(As + sr * 128 + ((sp ^ (sr & 7)) << 4)) = o;
    #pragma unroll
    for (int q = 0; q < 8; ++q)
      *(u16x8*)(Bs + tid * 128 + ((q ^ (tid & 7)) << 4)) = br[q];
  };

  for (int t = t0; t < t1; ++t) {
    if (t == t0) LOADREGS(t);
    else __syncthreads();             // previous compute done reading LDS
    WRITELDS();
    if (t + 1 < t1) LOADREGS(t + 1);  // prefetch next tile during compute
    __syncthreads();
    #pragma unroll
    for (int ks = 0; ks < 2; ++ks) {
      bf16x8 af[4]; bf16x8 bfr[4];
      int kg = ks * 4 + (lane >> 4);
      #pragma unroll
      for (int i = 0; i < 4; ++i) {
        int r = i * 16 + (lane & 15);
        af[i] = *(const bf16x8*)(As + r * 128 + ((kg ^ (r & 7)) << 4));
      }
      #pragma unroll
      for (int j = 0; j < 4; ++j) {
        int n = wave * 64 + j * 16 + (lane & 15);
        bfr[j] = *(const bf16x8*)(Bs + n * 128 + ((kg ^ (n & 7)) << 4));
      }
      #pragma unroll
      for (int i = 0; i < 4; ++i)
        #pragma unroll
        for (int j = 0; j < 4; ++j)
          acc[i][j] = __builtin_amdgcn_mfma_f32_16x16x32_bf16(af[i], bfr[j], acc[i][j], 0, 0, 0);
    }
  }

  float* Cb = Ppart + (size_t)ksp * (8192 * 512);
  #pragma unroll
  for (int i = 0; i < 4; ++i) {
    #pragma unroll
    for (int j = 0; j < 4; ++j) {
      int row = m0 + i * 16 + ((lane >> 4) << 2);
      int col = wave * 64 + j * 16 + (lane & 15);
      #pragma unroll
      for (int rr = 0; rr < 4; ++rr)
        Cb[(size_t)(row + rr) * 512 + col] = acc[i][j][rr];
    }
  }
}

// C[M][ldc] (f32) = A[M][K] * BT[n][k]^T.  Tile 128x64, BK=64, 4 waves (2x2) of 64x32.
// A = bf16 dense [M][512]  (highway layers)
__global__ __launch_bounds__(256)
void gemm_mfma(const unsigned short* __restrict__ Ap, const unsigned short* __restrict__ BT,
               float* __restrict__ C, int Kp, int ldc, int nK) {
  __shared__ char As[128 * 128];
  __shared__ char Bs[64 * 128];
  const int tid  = threadIdx.x;
  const int lane = tid & 63;
  const int wave = tid >> 6;
  const int wm = wave >> 1, wn = wave & 1;
  const int m0 = blockIdx.y * 128;
  const int n0 = blockIdx.x * 64;

  const int sr = tid >> 1, sp = tid & 1;
  const unsigned short* arow16 = Ap + (size_t)(m0 + sr) * HIDD;
  const int bn = tid >> 2;
  const unsigned short* brow = BT + (size_t)(n0 + bn) * Kp;

  f32x4 acc[4][2];
  #pragma unroll
  for (int i = 0; i < 4; ++i)
    #pragma unroll
    for (int j = 0; j < 2; ++j) acc[i][j] = (f32x4){0.f, 0.f, 0.f, 0.f};

  u16x8 ar16[4];
  u16x8 br[2];

  auto LOADREGS = [&](int t) {
    int k0 = t * 64;
    #pragma unroll
    for (int j = 0; j < 4; ++j) {
      int g = sp * 4 + j;
      ar16[j] = *(const u16x8*)(arow16 + k0 + g * 8);
    }
    #pragma unroll
    for (int q = 0; q < 2; ++q) {
      int g = (tid & 3) * 2 + q;
      br[q] = *(const u16x8*)(brow + k0 + g * 8);
    }
  };

  auto WRITELDS = [&]() {
    #pragma unroll
    for (int j = 0; j < 4; ++j) {
      int g = sp * 4 + j;
      *(u16x8*)(As + sr * 128 + ((g ^ (sr & 7)) << 4)) = ar16[j];
    }
    #pragma unroll
    for (int q = 0; q < 2; ++q) {
      int g = (tid & 3) * 2 + q;
      *(u16x8*)(Bs + bn * 128 + ((g ^ (bn & 7)) << 4)) = br[q];
    }
  };

  for (int t = 0; t < nK; ++t) {
    if (t == 0) LOADREGS(0);
    else __syncthreads();
    WRITELDS();
    if (t + 1 < nK) LOADREGS(t + 1);
    __syncthreads();
    #pragma unroll
    for (int ks = 0; ks < 2; ++ks) {
      bf16x8 af[4]; bf16x8 bfr[2];
      int kg = ks * 4 + (lane >> 4);
      #pragma unroll
      for (int i = 0; i < 4; ++i) {
        int r = wm * 64 + i * 16 + (lane & 15);
        af[i] = *(const bf16x8*)(As + r * 128 + ((kg ^ (r & 7)) << 4));
      }
      #pragma unroll
      for (int j = 0; j < 2; ++j) {
        int n = wn * 32 + j * 16 + (lane & 15);
        bfr[j] = *(const bf16x8*)(Bs + n * 128 + ((kg ^ (n & 7)) << 4));
      }
      #pragma unroll
      for (int i = 0; i < 4; ++i)
        #pragma unroll
        for (int j = 0; j < 2; ++j)
          acc[i][j] = __builtin_amdgcn_mfma_f32_16x16x32_bf16(af[i], bfr[j], acc[i][j], 0, 0, 0);
    }
  }

  #pragma unroll
  for (int i = 0; i < 4; ++i) {
    #pragma unroll
    for (int j = 0; j < 2; ++j) {
      int row = m0 + wm * 64 + i * 16 + ((lane >> 4) << 2);
      int col = n0 + wn * 32 + j * 16 + (lane & 15);
      #pragma unroll
      for (int rr = 0; rr < 4; ++rr)
        C[(size_t)(row + rr) * ldc + col] = acc[i][j][rr];
    }
  }
}

// ex = relu(P0+P1) rows [0,4096), ey rows [4096,8192); xb = bf16((ex-ey)^2/sqrt(512))
__global__ void pair_combine(const float* __restrict__ P, unsigned short* __restrict__ xb) {
  int i = blockIdx.x * 256 + threadIdx.x;  // over 4096*512/4 float4 groups
  const size_t half = (size_t)8192 * 512 / 4;   // partial-1 offset in float4s
  const size_t yoff = (size_t)BP * HIDD / 4;    // ey offset in float4s
  const float4 a0 = ((const float4*)P)[i];
  const float4 a1 = ((const float4*)P)[i + half];
  const float4 b0 = ((const float4*)P)[i + yoff];
  const float4 b1 = ((const float4*)P)[i + yoff + half];
  const float s = 0.04419417382415922f;    // 1/sqrt(512)
  float ex, ey, d;
  u16x4 o;
  ex = fmaxf(a0.x + a1.x, 0.f); ey = fmaxf(b0.x + b1.x, 0.f); d = ex - ey; o[0] = f2bf(d * d * s);
  ex = fmaxf(a0.y + a1.y, 0.f); ey = fmaxf(b0.y + b1.y, 0.f); d = ex - ey; o[1] = f2bf(d * d * s);
  ex = fmaxf(a0.z + a1.z, 0.f); ey = fmaxf(b0.z + b1.z, 0.f); d = ex - ey; o[2] = f2bf(d * d * s);
  ex = fmaxf(a0.w + a1.w, 0.f); ey = fmaxf(b0.w + b1.w, 0.f); d = ex - ey; o[3] = f2bf(d * d * s);
  ((u16x4*)xb)[i] = o;
}

// highway combine: xout = relu(hg[:, :512]+bh) * t + x * (1-t),  t = sigmoid(hg[:, 512:]+bg)
__global__ void hwy_elem(const float* __restrict__ hg, const unsigned short* __restrict__ xin,
                         const float* __restrict__ bh, const float* __restrict__ bg,
                         unsigned short* __restrict__ xout) {
  int i = blockIdx.x * 256 + threadIdx.x;  // 4096*512
  int m = i >> 9, h = i & 511;
  float hv = hg[(size_t)m * 1024 + h] + bh[h];
  hv = fmaxf(hv, 0.f);
  float gv = hg[(size_t)m * 1024 + 512 + h] + bg[h];
  float tv = 1.f / (1.f + expf(-gv));
  float xi = bf2f(xin[i]);
  xout[i] = f2bf(hv * tv + xi * (1.f - tv));
}

// logits + 2-class log_softmax, one wave per row
__global__ void logits_lsm(const unsigned short* __restrict__ x2, const float* __restrict__ Wl,
                           const float* __restrict__ bl, float* __restrict__ out) {
  int gw = (blockIdx.x * blockDim.x + threadIdx.x) >> 6;
  int lane = threadIdx.x & 63;
  const unsigned short* xr = x2 + (size_t)gw * HIDD;
  u16x8 xv = *(const u16x8*)(xr + lane * 8);
  float4 w0 = ((const float4*)Wl)[lane * 4 + 0];
  float4 w1 = ((const float4*)Wl)[lane * 4 + 1];
  float4 w2 = ((const float4*)Wl)[lane * 4 + 2];
  float4 w3 = ((const float4*)Wl)[lane * 4 + 3];
  float xs[8];
  #pragma unroll
  for (int j = 0; j < 8; ++j) xs[j] = bf2f(xv[j]);
  float s0 = xs[0]*w0.x + xs[1]*w0.z + xs[2]*w1.x + xs[3]*w1.z
           + xs[4]*w2.x + xs[5]*w2.z + xs[6]*w3.x + xs[7]*w3.z;
  float s1 = xs[0]*w0.y + xs[1]*w0.w + xs[2]*w1.y + xs[3]*w1.w
           + xs[4]*w2.y + xs[5]*w2.w + xs[6]*w3.y + xs[7]*w3.w;
  #pragma unroll
  for (int off = 32; off; off >>= 1) { s0 += __shfl_down(s0, off); s1 += __shfl_down(s1, off); }
  if (lane == 0) {
    float l0 = s0 + bl[0], l1 = s1 + bl[1];
    float mx = fmaxf(l0, l1);
    float lse = mx + logf(expf(l0 - mx) + expf(l1 - mx));
    out[(size_t)gw * 2 + 0] = l0 - lse;
    out[(size_t)gw * 2 + 1] = l1 - lse;
  }
}

extern "C" void kernel_launch(void* const* d_in, const int* in_sizes, int n_in,
                              void* d_out, int out_size, void* d_ws, size_t ws_size,
                              hipStream_t stream) {
  const float* A   = (const float*)d_in[0];
  const float* W1  = (const float*)d_in[1];
  const float* Wh0 = (const float*)d_in[2];
  const float* bh0 = (const float*)d_in[3];
  const float* Wg0 = (const float*)d_in[4];
  const float* bg0 = (const float*)d_in[5];
  const float* Wh1 = (const float*)d_in[6];
  const float* bh1 = (const float*)d_in[7];
  const float* Wg1 = (const float*)d_in[8];
  const float* bg1 = (const float*)d_in[9];
  const float* Wl  = (const float*)d_in[10];
  const float* bl  = (const float*)d_in[11];
  const int* idxx  = (const int*)d_in[12];
  const int* idxy  = (const int*)d_in[13];
  float* out = (float*)d_out;

  char* w = (char*)d_ws;
  auto carve = [&](size_t bytes) { char* p = w; w += (bytes + 255) & ~(size_t)255; return p; };
  unsigned short* W1T  = (unsigned short*)carve((size_t)512 * KPAD * 2);
  unsigned short* WcT0 = (unsigned short*)carve((size_t)1024 * 512 * 2);
  unsigned short* WcT1 = (unsigned short*)carve((size_t)1024 * 512 * 2);
  float* Ppart         = (float*)carve((size_t)2 * 8192 * 512 * 4);  // 2 K-split partials
  unsigned short* xb0  = (unsigned short*)carve((size_t)4096 * 512 * 2);
  unsigned short* xb1  = (unsigned short*)carve((size_t)4096 * 512 * 2);
  unsigned short* xb2  = (unsigned short*)carve((size_t)4096 * 512 * 2);
  float* hg            = Ppart;   // overlay: Ppart dead after pair_combine (16 MB < 32 MB)

  // weight prep (runs every call; ~31 MB traffic)
  transpose_cvt<<<dim3(KPAD / 32, 16), 256, 0, stream>>>(W1, W1T, NN, KPAD);
  transpose_cvt<<<dim3(16, 16), 256, 0, stream>>>(Wh0, WcT0, 512, 512);
  transpose_cvt<<<dim3(16, 16), 256, 0, stream>>>(Wg0, WcT0 + (size_t)512 * 512, 512, 512);
  transpose_cvt<<<dim3(16, 16), 256, 0, stream>>>(Wh1, WcT1, 512, 512);
  transpose_cvt<<<dim3(16, 16), 256, 0, stream>>>(Wg1, WcT1 + (size_t)512 * 512, 512, 512);

  // Ppart[ks] = A[gathered rows] @ W1  (K split in 2; 256 blocks = 1 round on 256 CUs)
  gather_gemm<<<dim3(2, 128), 512, 0, stream>>>(A, W1T, Ppart, idxx, idxy);
  pair_combine<<<dim3(2048), 256, 0, stream>>>(Ppart, xb0);

  // highway layer 0
  gemm_mfma<<<dim3(16, 32), 256, 0, stream>>>(xb0, WcT0, hg, 512, 1024, 8);
  hwy_elem<<<dim3(8192), 256, 0, stream>>>(hg, xb0, bh0, bg0, xb1);

  // highway layer 1
  gemm_mfma<<<dim3(16, 32), 256, 0, stream>>>(xb1, WcT1, hg, 512, 1024, 8);
  hwy_elem<<<dim3(8192), 256, 0, stream>>>(hg, xb1, bh1, bg1, xb2);

  logits_lsm<<<dim3(1024), 256, 0, stream>>>(xb2, Wl, bl, out);
}

// Round 3
// 193.755 us; speedup vs baseline: 3.3909x; 1.4504x over previous
//
#include <hip/hip_runtime.h>
#include <hip/hip_bf16.h>
#include <math.h>

#define NN   10000
#define HIDD 512
#define BP   4096
#define KPAD 10048      // 157 * 64
#define KITER1 157
#define KSPLIT 4

typedef short bf16x8 __attribute__((ext_vector_type(8)));
typedef float f32x4  __attribute__((ext_vector_type(4)));
typedef unsigned short u16x4 __attribute__((ext_vector_type(4)));
typedef unsigned short u16x8 __attribute__((ext_vector_type(8)));

__device__ __forceinline__ unsigned short f2bf(float f) {
  union { float f; unsigned u; } v; v.f = f;
  unsigned r = v.u + 0x7FFFu + ((v.u >> 16) & 1u);   // RN-even
  return (unsigned short)(r >> 16);
}
__device__ __forceinline__ float bf2f(unsigned short u) {
  union { unsigned u; float f; } v; v.u = ((unsigned)u) << 16;
  return v.f;
}
__device__ __forceinline__ void gload_lds16(const void* g, void* l) {
  __builtin_amdgcn_global_load_lds((const __attribute__((address_space(1))) unsigned int*)g,
                                   (__attribute__((address_space(3))) unsigned int*)l, 16, 0, 0);
}

// src f32 [K][512] -> dst bf16 [512][Kpadw], zero-padded for k in [K, Kpadw)
__global__ void transpose_cvt(const float* __restrict__ src, unsigned short* __restrict__ dst,
                              int K, int Kpadw) {
  __shared__ float tile[32][33];
  int k0 = blockIdx.x * 32, n0 = blockIdx.y * 32;
  int t = threadIdx.x, c = t & 31, r = t >> 5;
  #pragma unroll
  for (int i = 0; i < 4; ++i) {
    int k = k0 + r + i * 8;
    float v = (k < K) ? src[(size_t)k * 512 + (n0 + c)] : 0.f;
    tile[r + i * 8][c] = v;
  }
  __syncthreads();
  #pragma unroll
  for (int i = 0; i < 4; ++i) {
    int n = n0 + r + i * 8;
    dst[(size_t)n * Kpadw + (k0 + c)] = f2bf(tile[c][r + i * 8]);
  }
}

// Gather-GEMM: Ppart[ksp][8192][512] = A[gather rows] @ W1T^T over K-chunk ksp.
// Tile 64(m) x 512(n) x BK=64, 512 threads = 8 waves, wave-tile 64x64.
// A rows read EXACTLY ONCE from HBM; B staged via global_load_lds with
// swizzle folded into the per-lane global source address (linear LDS dest).
__global__ __launch_bounds__(512, 4)
void gather_gemm(const float* __restrict__ A, const unsigned short* __restrict__ BT,
                 float* __restrict__ Ppart,
                 const int* __restrict__ idxx, const int* __restrict__ idxy) {
  __shared__ char As[64 * 128];    // 64 rows x 64 bf16, XOR-swizzled 16B granules
  __shared__ char Bs[512 * 128];   // 512 n-rows x 64 bf16, swizzle via source addr
  const int tid  = threadIdx.x;
  const int lane = tid & 63;
  const int wave = tid >> 6;                  // 0..7, owns n-range [wave*64, +64)
  const int m0   = blockIdx.y * 64;
  const int ksp  = blockIdx.x;                // 0..3
  const int t0   = (ksp * KITER1) / KSPLIT;
  const int t1   = ((ksp + 1) * KITER1) / KSPLIT;

  // A staging: 8 threads per row, each 8 consecutive floats
  const int sr = tid >> 3, sp = tid & 7;
  int m = m0 + sr;
  int g = (m < BP) ? idxx[m] : idxy[m - BP];
  const float* arow = A + (size_t)g * NN;

  // B staging via global_load_lds: per wave 8 instrs of 1 KB; lane l covers
  // row r = wave*64 + j*8 + (l>>3), LDS granule slot q=l&7 which must hold
  // global granule q ^ (r&7) = (l&7) ^ (l>>3).
  const int brow0 = wave * 64 + (lane >> 3);
  const int bq    = (lane & 7) ^ (lane >> 3);
  const unsigned short* bsrc = BT + (size_t)brow0 * KPAD + bq * 8 + t0 * 64;
  char* bdst = Bs + wave * 8192;

  f32x4 acc[4][4];
  #pragma unroll
  for (int i = 0; i < 4; ++i)
    #pragma unroll
    for (int j = 0; j < 4; ++j) acc[i][j] = (f32x4){0.f, 0.f, 0.f, 0.f};

  float4 ar[2];

  auto LOADA = [&](int t) {
    int ka = t * 64 + sp * 8;
    if (ka < NN) {
      ar[0] = *(const float4*)(arow + ka);
      ar[1] = *(const float4*)(arow + ka + 4);
    } else {
      ar[0] = make_float4(0.f, 0.f, 0.f, 0.f);
      ar[1] = make_float4(0.f, 0.f, 0.f, 0.f);
    }
  };
  auto ISSUEB = [&](int t) {
    const unsigned short* s = bsrc + (size_t)(t - t0) * 64;
    #pragma unroll
    for (int j = 0; j < 8; ++j)
      gload_lds16(s + (size_t)j * 8 * KPAD, bdst + j * 1024);
  };
  auto WRITEA = [&]() {
    u16x8 o;
    o[0] = f2bf(ar[0].x); o[1] = f2bf(ar[0].y); o[2] = f2bf(ar[0].z); o[3] = f2bf(ar[0].w);
    o[4] = f2bf(ar[1].x); o[5] = f2bf(ar[1].y); o[6] = f2bf(ar[1].z); o[7] = f2bf(ar[1].w);
    *(u16x8*)(As + sr * 128 + ((sp ^ (sr & 7)) << 4)) = o;
  };

  LOADA(t0);
  ISSUEB(t0);
  for (int t = t0; t < t1; ++t) {
    WRITEA();                         // waits A regs (counted vmcnt), ds_write
    __syncthreads();                  // drains B-lds: Bs(t) ready, As visible
    if (t + 1 < t1) LOADA(t + 1);     // A prefetch rides under compute
    #pragma unroll
    for (int ks = 0; ks < 2; ++ks) {
      bf16x8 af[4]; bf16x8 bfr[4];
      int kg = ks * 4 + (lane >> 4);
      #pragma unroll
      for (int i = 0; i < 4; ++i) {
        int r = i * 16 + (lane & 15);
        af[i] = *(const bf16x8*)(As + r * 128 + ((kg ^ (r & 7)) << 4));
      }
      #pragma unroll
      for (int j = 0; j < 4; ++j) {
        int n = wave * 64 + j * 16 + (lane & 15);
        bfr[j] = *(const bf16x8*)(Bs + n * 128 + ((kg ^ (n & 7)) << 4));
      }
      #pragma unroll
      for (int i = 0; i < 4; ++i)
        #pragma unroll
        for (int j = 0; j < 4; ++j)
          acc[i][j] = __builtin_amdgcn_mfma_f32_16x16x32_bf16(af[i], bfr[j], acc[i][j], 0, 0, 0);
    }
    __syncthreads();                  // all waves done reading LDS(t)
    if (t + 1 < t1) ISSUEB(t + 1);    // refill Bs for next iter
  }

  float* Cb = Ppart + (size_t)ksp * (8192 * 512);
  #pragma unroll
  for (int i = 0; i < 4; ++i) {
    #pragma unroll
    for (int j = 0; j < 4; ++j) {
      int row = m0 + i * 16 + ((lane >> 4) << 2);
      int col = wave * 64 + j * 16 + (lane & 15);
      #pragma unroll
      for (int rr = 0; rr < 4; ++rr)
        Cb[(size_t)(row + rr) * 512 + col] = acc[i][j][rr];
    }
  }
}

// Fused highway layer: for tile of 128 rows x 64 h-cols, compute both
// h = x@Wh + bh and g = x@Wg + bg (Bs holds Wh^T rows n0.. and Wg^T rows 512+n0..),
// then epilogue: xout = relu(h)*sigmoid(g) + x*(1-sigmoid(g)), bf16.
__global__ __launch_bounds__(256)
void hwy_gemm(const unsigned short* __restrict__ xin, const unsigned short* __restrict__ WcT,
              const float* __restrict__ bh, const float* __restrict__ bg,
              unsigned short* __restrict__ xout) {
  __shared__ char As[128 * 128];
  __shared__ char Bs[128 * 128];   // rows 0-63: Wh^T n0+..; rows 64-127: Wg^T 512+n0+..
  const int tid  = threadIdx.x;
  const int lane = tid & 63;
  const int wave = tid >> 6;
  const int wm = wave >> 1, wn = wave & 1;
  const int m0 = blockIdx.y * 128;
  const int n0 = blockIdx.x * 64;

  const int sr = tid >> 1, sp = tid & 1;
  const unsigned short* arow16 = xin + (size_t)(m0 + sr) * HIDD;
  const int rb = tid >> 1;         // B LDS row 0..127
  const int grow = (rb < 64) ? (n0 + rb) : (512 + n0 + rb - 64);
  const unsigned short* brow = WcT + (size_t)grow * HIDD;

  f32x4 acc[4][2][2];
  #pragma unroll
  for (int i = 0; i < 4; ++i)
    #pragma unroll
    for (int j = 0; j < 2; ++j)
      #pragma unroll
      for (int p = 0; p < 2; ++p) acc[i][j][p] = (f32x4){0.f, 0.f, 0.f, 0.f};

  u16x8 ar16[4], br16[4];

  auto LOADREGS = [&](int t) {
    int k0 = t * 64;
    #pragma unroll
    for (int j = 0; j < 4; ++j)
      ar16[j] = *(const u16x8*)(arow16 + k0 + (sp * 4 + j) * 8);
    #pragma unroll
    for (int q = 0; q < 4; ++q)
      br16[q] = *(const u16x8*)(brow + k0 + (sp * 4 + q) * 8);
  };
  auto WRITELDS = [&]() {
    #pragma unroll
    for (int j = 0; j < 4; ++j) {
      int g = sp * 4 + j;
      *(u16x8*)(As + sr * 128 + ((g ^ (sr & 7)) << 4)) = ar16[j];
    }
    #pragma unroll
    for (int q = 0; q < 4; ++q) {
      int g = sp * 4 + q;
      *(u16x8*)(Bs + rb * 128 + ((g ^ (rb & 7)) << 4)) = br16[q];
    }
  };

  for (int t = 0; t < 8; ++t) {
    if (t == 0) LOADREGS(0);
    else __syncthreads();
    WRITELDS();
    if (t + 1 < 8) LOADREGS(t + 1);
    __syncthreads();
    #pragma unroll
    for (int ks = 0; ks < 2; ++ks) {
      bf16x8 af[4]; bf16x8 bfr[2][2];
      int kg = ks * 4 + (lane >> 4);
      #pragma unroll
      for (int i = 0; i < 4; ++i) {
        int r = wm * 64 + i * 16 + (lane & 15);
        af[i] = *(const bf16x8*)(As + r * 128 + ((kg ^ (r & 7)) << 4));
      }
      #pragma unroll
      for (int j = 0; j < 2; ++j)
        #pragma unroll
        for (int p = 0; p < 2; ++p) {
          int n = p * 64 + wn * 32 + j * 16 + (lane & 15);
          bfr[j][p] = *(const bf16x8*)(Bs + n * 128 + ((kg ^ (n & 7)) << 4));
        }
      #pragma unroll
      for (int i = 0; i < 4; ++i)
        #pragma unroll
        for (int j = 0; j < 2; ++j)
          #pragma unroll
          for (int p = 0; p < 2; ++p)
            acc[i][j][p] = __builtin_amdgcn_mfma_f32_16x16x32_bf16(af[i], bfr[j][p], acc[i][j][p], 0, 0, 0);
    }
  }

  #pragma unroll
  for (int j = 0; j < 2; ++j) {
    int col = n0 + wn * 32 + j * 16 + (lane & 15);
    float bhv = bh[col], bgv = bg[col];
    #pragma unroll
    for (int i = 0; i < 4; ++i) {
      int row = m0 + wm * 64 + i * 16 + ((lane >> 4) << 2);
      #pragma unroll
      for (int rr = 0; rr < 4; ++rr) {
        float hv = fmaxf(acc[i][j][0][rr] + bhv, 0.f);
        float gv = acc[i][j][1][rr] + bgv;
        float tv = 1.f / (1.f + expf(-gv));
        float xi = bf2f(xin[(size_t)(row + rr) * HIDD + col]);
        xout[(size_t)(row + rr) * HIDD + col] = f2bf(hv * tv + xi * (1.f - tv));
      }
    }
  }
}

// ex = relu(sum of 4 partials), rows [0,4096)=ex, [4096,8192)=ey
__global__ void pair_combine(const float* __restrict__ P, unsigned short* __restrict__ xb) {
  int i = blockIdx.x * 256 + threadIdx.x;       // 4096*512/4 float4 groups
  const size_t qs = (size_t)8192 * 512 / 4;     // per-partial size in float4s
  const size_t yoff = (size_t)BP * HIDD / 4;    // ey offset in float4s
  float4 a = ((const float4*)P)[i];
  float4 b = ((const float4*)P)[i + yoff];
  #pragma unroll
  for (int q = 1; q < KSPLIT; ++q) {
    float4 aq = ((const float4*)P)[i + q * qs];
    float4 bq = ((const float4*)P)[i + yoff + q * qs];
    a.x += aq.x; a.y += aq.y; a.z += aq.z; a.w += aq.w;
    b.x += bq.x; b.y += bq.y; b.z += bq.z; b.w += bq.w;
  }
  const float s = 0.04419417382415922f;    // 1/sqrt(512)
  float ex, ey, d;
  u16x4 o;
  ex = fmaxf(a.x, 0.f); ey = fmaxf(b.x, 0.f); d = ex - ey; o[0] = f2bf(d * d * s);
  ex = fmaxf(a.y, 0.f); ey = fmaxf(b.y, 0.f); d = ex - ey; o[1] = f2bf(d * d * s);
  ex = fmaxf(a.z, 0.f); ey = fmaxf(b.z, 0.f); d = ex - ey; o[2] = f2bf(d * d * s);
  ex = fmaxf(a.w, 0.f); ey = fmaxf(b.w, 0.f); d = ex - ey; o[3] = f2bf(d * d * s);
  ((u16x4*)xb)[i] = o;
}

// logits + 2-class log_softmax, one wave per row
__global__ void logits_lsm(const unsigned short* __restrict__ x2, const float* __restrict__ Wl,
                           const float* __restrict__ bl, float* __restrict__ out) {
  int gw = (blockIdx.x * blockDim.x + threadIdx.x) >> 6;
  int lane = threadIdx.x & 63;
  const unsigned short* xr = x2 + (size_t)gw * HIDD;
  u16x8 xv = *(const u16x8*)(xr + lane * 8);
  float4 w0 = ((const float4*)Wl)[lane * 4 + 0];
  float4 w1 = ((const float4*)Wl)[lane * 4 + 1];
  float4 w2 = ((const float4*)Wl)[lane * 4 + 2];
  float4 w3 = ((const float4*)Wl)[lane * 4 + 3];
  float xs[8];
  #pragma unroll
  for (int j = 0; j < 8; ++j) xs[j] = bf2f(xv[j]);
  float s0 = xs[0]*w0.x + xs[1]*w0.z + xs[2]*w1.x + xs[3]*w1.z
           + xs[4]*w2.x + xs[5]*w2.z + xs[6]*w3.x + xs[7]*w3.z;
  float s1 = xs[0]*w0.y + xs[1]*w0.w + xs[2]*w1.y + xs[3]*w1.w
           + xs[4]*w2.y + xs[5]*w2.w + xs[6]*w3.y + xs[7]*w3.w;
  #pragma unroll
  for (int off = 32; off; off >>= 1) { s0 += __shfl_down(s0, off); s1 += __shfl_down(s1, off); }
  if (lane == 0) {
    float l0 = s0 + bl[0], l1 = s1 + bl[1];
    float mx = fmaxf(l0, l1);
    float lse = mx + logf(expf(l0 - mx) + expf(l1 - mx));
    out[(size_t)gw * 2 + 0] = l0 - lse;
    out[(size_t)gw * 2 + 1] = l1 - lse;
  }
}

extern "C" void kernel_launch(void* const* d_in, const int* in_sizes, int n_in,
                              void* d_out, int out_size, void* d_ws, size_t ws_size,
                              hipStream_t stream) {
  const float* A   = (const float*)d_in[0];
  const float* W1  = (const float*)d_in[1];
  const float* Wh0 = (const float*)d_in[2];
  const float* bh0 = (const float*)d_in[3];
  const float* Wg0 = (const float*)d_in[4];
  const float* bg0 = (const float*)d_in[5];
  const float* Wh1 = (const float*)d_in[6];
  const float* bh1 = (const float*)d_in[7];
  const float* Wg1 = (const float*)d_in[8];
  const float* bg1 = (const float*)d_in[9];
  const float* Wl  = (const float*)d_in[10];
  const float* bl  = (const float*)d_in[11];
  const int* idxx  = (const int*)d_in[12];
  const int* idxy  = (const int*)d_in[13];
  float* out = (float*)d_out;

  char* w = (char*)d_ws;
  auto carve = [&](size_t bytes) { char* p = w; w += (bytes + 255) & ~(size_t)255; return p; };
  unsigned short* W1T  = (unsigned short*)carve((size_t)512 * KPAD * 2);
  unsigned short* WcT0 = (unsigned short*)carve((size_t)1024 * 512 * 2);
  unsigned short* WcT1 = (unsigned short*)carve((size_t)1024 * 512 * 2);
  float* Ppart         = (float*)carve((size_t)KSPLIT * 8192 * 512 * 4);
  unsigned short* xb0  = (unsigned short*)carve((size_t)4096 * 512 * 2);
  unsigned short* xb1  = (unsigned short*)carve((size_t)4096 * 512 * 2);
  unsigned short* xb2  = (unsigned short*)carve((size_t)4096 * 512 * 2);

  // weight prep (~31 MB traffic)
  transpose_cvt<<<dim3(KPAD / 32, 16), 256, 0, stream>>>(W1, W1T, NN, KPAD);
  transpose_cvt<<<dim3(16, 16), 256, 0, stream>>>(Wh0, WcT0, 512, 512);
  transpose_cvt<<<dim3(16, 16), 256, 0, stream>>>(Wg0, WcT0 + (size_t)512 * 512, 512, 512);
  transpose_cvt<<<dim3(16, 16), 256, 0, stream>>>(Wh1, WcT1, 512, 512);
  transpose_cvt<<<dim3(16, 16), 256, 0, stream>>>(Wg1, WcT1 + (size_t)512 * 512, 512, 512);

  // Ppart[ksp] = A[gathered rows] @ W1 K-chunk  (512 blocks = 2/CU)
  gather_gemm<<<dim3(KSPLIT, 128), 512, 0, stream>>>(A, W1T, Ppart, idxx, idxy);
  pair_combine<<<dim3(2048), 256, 0, stream>>>(Ppart, xb0);

  // fused highway layers
  hwy_gemm<<<dim3(8, 32), 256, 0, stream>>>(xb0, WcT0, bh0, bg0, xb1);
  hwy_gemm<<<dim3(8, 32), 256, 0, stream>>>(xb1, WcT1, bh1, bg1, xb2);

  logits_lsm<<<dim3(1024), 256, 0, stream>>>(xb2, Wl, bl, out);
}